// Round 11
// baseline (265.596 us; speedup 1.0000x reference)
//
#include <hip/hip_runtime.h>
#include <cfloat>

#define B_ 8
#define C_ 64
#define N_ 4096
#define K_ 20
#define MARGIN 0.08f
#define CAP 64

typedef float f32x4v  __attribute__((ext_vector_type(4)));
typedef float f32x16v __attribute__((ext_vector_type(16)));
typedef _Float16 f16x8 __attribute__((ext_vector_type(8)));
typedef unsigned long long u64;

// ws layout (bytes):
//   xxn : B*N floats (= -xx/2, fp64-accumulated)  @ 0
//   idx : B*N*20 ints                             @ 131072
//   qg  : B*N*128 floats [b][m][o2]               @ 2752512  (16 MB)
//         -- ALSO used (before k_qg runs) as bufg: B*N*CAP u64 = 16 MB exact
//   P0  : [b][seg=c/8][m][j=c%8] f16 limb0        @ 19529728 (4 MB)
//   P1  : limb1 (scale 2^-12)                     @ 23724032 (4 MB)
#define OFF_IDX 131072
#define OFF_QG  2752512
#define OFF_P0  19529728
#define OFF_P1  23724032

// ---------------- Kernel 1: 2-limb fp16 split + (-xx/2) ----------------
__global__ __launch_bounds__(256) void k_split(const float* __restrict__ x,
                                               unsigned short* __restrict__ p0,
                                               unsigned short* __restrict__ p1,
                                               float* __restrict__ xxn) {
    int b = blockIdx.x & 7, mt = blockIdx.x >> 3;
    int m = mt * 256 + threadIdx.x;
    const float* xb = x + (size_t)b * C_ * N_;
    double ss = 0.0;
#pragma unroll 1
    for (int seg = 0; seg < 8; ++seg) {
        unsigned short h0[8], h1[8];
#pragma unroll
        for (int j = 0; j < 8; ++j) {
            float v = xb[(size_t)(seg * 8 + j) * N_ + m];
            ss += (double)v * (double)v;
            _Float16 a = (_Float16)v;
            float r = v - (float)a;
            _Float16 bq = (_Float16)(r * 4096.f);
            h0[j] = __builtin_bit_cast(unsigned short, a);
            h1[j] = __builtin_bit_cast(unsigned short, bq);
        }
        uint4 q0, q1;
        q0.x = h0[0] | (h0[1] << 16); q0.y = h0[2] | (h0[3] << 16);
        q0.z = h0[4] | (h0[5] << 16); q0.w = h0[6] | (h0[7] << 16);
        q1.x = h1[0] | (h1[1] << 16); q1.y = h1[2] | (h1[3] << 16);
        q1.z = h1[4] | (h1[5] << 16); q1.w = h1[6] | (h1[7] << 16);
        size_t o16 = (size_t)(b * 8 + seg) * N_ + m;
        ((uint4*)p0)[o16] = q0;
        ((uint4*)p1)[o16] = q1;
    }
    xxn[b * N_ + m] = (float)(-0.5 * ss);
}

// ---------------- Kernel 2: kNN, barrier-free streaming scans ----------------
// grid 512 = 8b x 64nt (64 rows). block 512 = 8 waves: wg=w&1 rows, cs=w>>1
// candidate-quarter. A-fragments streamed from global (L2-resident panels) --
// NO LDS staging, NO per-chunk barriers (3 barriers total).
// Phase 1: 1-limb approx scan -> per-row 32-cand block maxima into M (LDS).
// Select:  t* = 20th of 128 maxima/row (pooled top-8, one-sided-safe);
//          T2 = t* - MARGIN. Validity: 20th-of-block-maxima <= 20th-of-scores
//          (+ approx error covered by MARGIN, r10-validated).
// Phase 2: 2-limb precise scan (16 MFMA, bit-identical to r10's score16),
//          emit (score,~idx) u64 keys >= T2 to GLOBAL bufg (CAP 64).
// Phase 3: guarded key load -> LDS, exact top-20 by key (r8/r9/r10-validated).
// LDS: M 0..33024 [64][129] | L 33024..41472 [64][33] | cnt 41472 | T2 41728
//      keys overlay 0..33280 (64 x 65 u64; M,L dead)
__global__ __launch_bounds__(512, 4) void k_topk(const unsigned short* __restrict__ p0g,
                                                 const unsigned short* __restrict__ p1g,
                                                 const float* __restrict__ xxn,
                                                 u64* __restrict__ bufg,
                                                 int* __restrict__ idxo) {
    __shared__ __align__(16) char smem[41984];
    int b = blockIdx.x & 7, nt = blockIdx.x >> 3;
    int n0 = nt * 64;
    int tid = threadIdx.x;
    int w = tid >> 6, l = tid & 63, h = l >> 5, mf = l & 31;
    int cs = w >> 1, wg = w & 1;
    int rowl = wg * 32 + mf;
    int b8 = b * 8;
    const f32x4v* g0 = (const f32x4v*)p0g;
    const f32x4v* g1 = (const f32x4v*)p1g;
    const float*  xxb = xxn + b * N_;
    float* Mp   = (float*)smem;                  // [64][129]
    float* Lp   = (float*)(smem + 33024);        // [64][33]
    int*   cntp = (int*)(smem + 41472);
    float* T2p  = (float*)(smem + 41728);
    const float c12 = 1.f / 4096.f;

    // B fragments (center rows), 2 limbs, register-resident
    f16x8 b0[4], b1[4];
#pragma unroll
    for (int kc = 0; kc < 4; ++kc) {
        int seg = kc * 2 + h;
        size_t gi = (size_t)(b8 + seg) * N_ + n0 + rowl;
        b0[kc] = __builtin_bit_cast(f16x8, g0[gi]);
        b1[kc] = __builtin_bit_cast(f16x8, g1[gi]);
    }

    // ======== Phase 1: barrier-free approx scan -> per-row block maxima ========
#pragma unroll 2
    for (int ti = 0; ti < 32; ++ti) {
        int mc = cs * 1024 + ti * 32;
        f32x16v acc;
#pragma unroll
        for (int g2i = 0; g2i < 4; ++g2i) {
            f32x4v xv = *(const f32x4v*)&xxb[mc + 4 * h + 8 * g2i];
#pragma unroll
            for (int q = 0; q < 4; ++q) acc[g2i * 4 + q] = xv[q];
        }
#pragma unroll
        for (int kc = 0; kc < 4; ++kc) {
            int seg = kc * 2 + h;
            f16x8 a0 = __builtin_bit_cast(f16x8, g0[(size_t)(b8 + seg) * N_ + mc + mf]);
            acc = __builtin_amdgcn_mfma_f32_32x32x16_f16(a0, b0[kc], acc, 0, 0, 0);
        }
        float m8[8];
#pragma unroll
        for (int r = 0; r < 8; ++r) m8[r] = fmaxf(acc[r], acc[r + 8]);
        float mx = fmaxf(fmaxf(fmaxf(m8[0], m8[1]), fmaxf(m8[2], m8[3])),
                         fmaxf(fmaxf(m8[4], m8[5]), fmaxf(m8[6], m8[7])));
        mx = fmaxf(mx, __shfl_xor(mx, 32));
        if (l < 32)
            Mp[rowl * 129 + cs * 32 + ti] = mx;
    }

    // ======== Select: t* = 20th of 128 maxima per row ========
    __syncthreads();
    if (tid < 256) {                             // 4 lanes per row, top-8 each
        int row = tid >> 2, q = tid & 3;
        const float* mrow = Mp + row * 129 + q * 32;
        float v8[8];
#pragma unroll
        for (int j = 0; j < 8; ++j) v8[j] = -FLT_MAX;
#pragma unroll
        for (int i = 0; i < 32; ++i) {
            float v = mrow[i];
#pragma unroll
            for (int j = 7; j >= 1; --j) {
                bool c1 = v > v8[j - 1];
                float nv = c1 ? v8[j - 1] : v;
                v8[j] = (v > v8[j]) ? nv : v8[j];
            }
            v8[0] = fmaxf(v8[0], v);
        }
        float* lp = Lp + row * 33 + q * 8;
#pragma unroll
        for (int j = 0; j < 8; ++j) lp[j] = v8[j];
    }
    __syncthreads();
    if (tid < 64) {                              // 4-way merge to the 20th
        const float* lp = Lp + tid * 33;
        float hv0 = lp[0], hv1 = lp[8], hv2 = lp[16], hv3 = lp[24];
        int p0 = 0, p1 = 0, p2 = 0, p3 = 0;
        float tstar = -FLT_MAX;
        for (int k = 0; k < 20; ++k) {
            bool a = hv0 >= hv1; float ma = a ? hv0 : hv1; int sa = a ? 0 : 1;
            bool bb = hv2 >= hv3; float mb = bb ? hv2 : hv3; int sb = bb ? 2 : 3;
            bool c = ma >= mb; tstar = c ? ma : mb; int sl = c ? sa : sb;
            if (sl == 0) { ++p0; hv0 = (p0 < 8) ? lp[p0] : -FLT_MAX; }
            else if (sl == 1) { ++p1; hv1 = (p1 < 8) ? lp[8 + p1] : -FLT_MAX; }
            else if (sl == 2) { ++p2; hv2 = (p2 < 8) ? lp[16 + p2] : -FLT_MAX; }
            else { ++p3; hv3 = (p3 < 8) ? lp[24 + p3] : -FLT_MAX; }
        }
        T2p[tid] = tstar - MARGIN;
        cntp[tid] = 0;
    }
    __syncthreads();
    float T2r = T2p[rowl];

    // ======== Phase 2: barrier-free precise scan + emit keys to global ========
#pragma unroll 1
    for (int ti = 0; ti < 32; ++ti) {
        int mc = cs * 1024 + ti * 32;
        f32x16v acc1, acc2, acc3;
#pragma unroll
        for (int g2i = 0; g2i < 4; ++g2i) {
            f32x4v xv = *(const f32x4v*)&xxb[mc + 4 * h + 8 * g2i];
#pragma unroll
            for (int q = 0; q < 4; ++q) {
                acc1[g2i * 4 + q] = xv[q];
                acc2[g2i * 4 + q] = 0.f;
                acc3[g2i * 4 + q] = 0.f;
            }
        }
#pragma unroll
        for (int kc = 0; kc < 4; ++kc) {
            int seg = kc * 2 + h;
            size_t gi = (size_t)(b8 + seg) * N_ + mc + mf;
            f16x8 a0 = __builtin_bit_cast(f16x8, g0[gi]);
            f16x8 a1 = __builtin_bit_cast(f16x8, g1[gi]);
            acc1 = __builtin_amdgcn_mfma_f32_32x32x16_f16(a0, b0[kc], acc1, 0, 0, 0);
            acc2 = __builtin_amdgcn_mfma_f32_32x32x16_f16(a0, b1[kc], acc2, 0, 0, 0);
            acc2 = __builtin_amdgcn_mfma_f32_32x32x16_f16(a1, b0[kc], acc2, 0, 0, 0);
            acc3 = __builtin_amdgcn_mfma_f32_32x32x16_f16(a1, b1[kc], acc3, 0, 0, 0);
        }
        float s[16];
#pragma unroll
        for (int r = 0; r < 16; ++r)
            s[r] = acc1[r] + (acc2[r] + acc3[r] * c12) * c12;
        unsigned msk = 0;
#pragma unroll
        for (int r = 0; r < 16; ++r) msk |= (s[r] >= T2r) ? (1u << r) : 0u;
        int cb = mc + 4 * h;
        while (msk) {
            int r = __ffs(msk) - 1;
            msk &= msk - 1;
            int cand = cb + (r & 3) + 8 * (r >> 2);
            float sv = s[r];
            unsigned sb = __float_as_uint(sv);
            unsigned kk = (sv < 0.f) ? ~sb : (sb | 0x80000000u);
            int slot = atomicAdd(cntp + rowl, 1);
            if (slot < CAP)
                bufg[((size_t)(b * N_ + n0 + rowl)) * CAP + slot] =
                    ((u64)kk << 32) | (unsigned)(~cand);
        }
    }

    // ======== Phase 3: load keys (guarded) + exact top-20 ========
    __syncthreads();
    u64* keys = (u64*)smem;                      // 64 x 65 u64 (padded stride)
#pragma unroll
    for (int i = 0; i < 8; ++i) {
        int p = i * 512 + tid;                   // 0..4095
        int row = p >> 6, slot = p & 63;
        int c_ = cntp[row]; c_ = (c_ > CAP) ? CAP : c_;
        u64 key = 0;
        if (slot < c_)
            key = bufg[((size_t)(b * N_ + n0 + row)) * CAP + slot];
        keys[row * (CAP + 1) + slot] = key;
    }
    __syncthreads();
    if (tid < 64) {
        int c_ = cntp[tid]; c_ = (c_ > CAP) ? CAP : c_;
        u64* kp = keys + tid * (CAP + 1);
        int* op = idxo + ((size_t)b * N_ + n0 + tid) * K_;
        for (int k = 0; k < K_; ++k) {
            u64 best = 0; int bs = 0;
            for (int s2 = 0; s2 < c_; ++s2) {
                bool g = kp[s2] > best;
                best = g ? kp[s2] : best;
                bs = g ? s2 : bs;
            }
            op[k] = (int)(~(unsigned)best) & 0xFFF;
            kp[bs] = 0;
        }
    }
}

// ---------------- Kernel 3: qg[b][m][o2]  (runs AFTER k_topk; overlays bufg) ---
__global__ __launch_bounds__(256) void k_qg(const float* __restrict__ x,
                                            const float* __restrict__ W,
                                            float* __restrict__ qg) {
    __shared__ float Wl[64 * 129];
    __shared__ float xs[64 * 64];
    int b = blockIdx.x & 7, mt = blockIdx.x >> 3;
    int mbase = mt * 64;
    int tid = threadIdx.x;

    for (int i = 0; i < 32; ++i) {
        int lin = tid + 256 * i;
        int c = lin & 63, o2 = lin >> 6;
        float wv;
        if (o2 < 64) wv = W[o2 * 128 + c];
        else { int o = o2 - 64; wv = W[o * 128 + 64 + c] - W[o * 128 + c]; }
        Wl[c * 129 + o2] = wv;
    }
#pragma unroll
    for (int i = 0; i < 4; ++i) {
        int lin = tid + 256 * i;
        int c = lin >> 4, f = lin & 15;
        *(float4*)&xs[c * 64 + f * 4] =
            *(const float4*)&x[((size_t)b * C_ + c) * N_ + mbase + f * 4];
    }
    __syncthreads();

    int u = tid & 63, half = tid >> 6;
    float a0[16], a1[16];
#pragma unroll
    for (int j = 0; j < 16; ++j) { a0[j] = 0.f; a1[j] = 0.f; }
#pragma unroll 4
    for (int c = 0; c < 64; ++c) {
        float2 wv = *(const float2*)&Wl[c * 129 + 2 * u];
        const float4* xr = (const float4*)&xs[c * 64 + half * 16];
        float4 v0 = xr[0], v1 = xr[1], v2 = xr[2], v3 = xr[3];
        float xvv[16];
        xvv[0]=v0.x; xvv[1]=v0.y; xvv[2]=v0.z; xvv[3]=v0.w;
        xvv[4]=v1.x; xvv[5]=v1.y; xvv[6]=v1.z; xvv[7]=v1.w;
        xvv[8]=v2.x; xvv[9]=v2.y; xvv[10]=v2.z; xvv[11]=v2.w;
        xvv[12]=v3.x; xvv[13]=v3.y; xvv[14]=v3.z; xvv[15]=v3.w;
#pragma unroll
        for (int j = 0; j < 16; ++j) { a0[j] += wv.x * xvv[j]; a1[j] += wv.y * xvv[j]; }
    }
#pragma unroll
    for (int j = 0; j < 16; ++j) {
        int m = mbase + half * 16 + j;
        float2 o; o.x = a0[j]; o.y = a1[j];
        *(float2*)&qg[((size_t)b * N_ + m) * 128 + 2 * u] = o;
    }
}

// ---------------- Kernel 4: out = max_k leaky(q[ik][o] + g[n][o]) ----------------
__global__ __launch_bounds__(256) void k_out(const float* __restrict__ qg,
                                             const int* __restrict__ idxi,
                                             float* __restrict__ out) {
    __shared__ float T[32][65];
    int b = blockIdx.x & 7, nt = blockIdx.x >> 3;
    int n0 = nt * 32;
    int tid = threadIdx.x;
    int w = tid >> 6, o = tid & 63;
    const float* qgb = qg + (size_t)b * N_ * 128;
    for (int i = 0; i < 8; ++i) {
        int nl = w * 8 + i;
        int n = n0 + nl;
        float gv = qgb[(size_t)n * 128 + 64 + o];
        const int* ip = idxi + ((size_t)b * N_ + n) * K_;
        float mx = -FLT_MAX;
#pragma unroll 5
        for (int k = 0; k < K_; ++k) {
            int ik = ip[k];
            float hh = qgb[(size_t)ik * 128 + o] + gv;
            hh = (hh >= 0.f) ? hh : 0.01f * hh;
            mx = fmaxf(mx, hh);
        }
        T[nl][o] = mx;
    }
    __syncthreads();
    int ow = tid >> 2, q = tid & 3;
#pragma unroll
    for (int j4 = 0; j4 < 2; ++j4) {
        int nl = q * 8 + j4 * 4;
        float4 v;
        v.x = T[nl + 0][ow]; v.y = T[nl + 1][ow];
        v.z = T[nl + 2][ow]; v.w = T[nl + 3][ow];
        *(float4*)&out[((size_t)b * 64 + ow) * N_ + n0 + nl] = v;
    }
}

extern "C" void kernel_launch(void* const* d_in, const int* in_sizes, int n_in,
                              void* d_out, int out_size, void* d_ws, size_t ws_size,
                              hipStream_t stream) {
    const float* x = (const float*)d_in[0];
    const float* W = (const float*)d_in[1];
    float* out = (float*)d_out;

    float*          xxn  = (float*)d_ws;
    int*            idx  = (int*)((char*)d_ws + OFF_IDX);
    float*          qg   = (float*)((char*)d_ws + OFF_QG);
    u64*            bufg = (u64*)((char*)d_ws + OFF_QG);   // overlays qg (topk before qg)
    unsigned short* p0   = (unsigned short*)((char*)d_ws + OFF_P0);
    unsigned short* p1   = (unsigned short*)((char*)d_ws + OFF_P1);

    k_split<<<dim3(128), dim3(256), 0, stream>>>(x, p0, p1, xxn);
    k_topk <<<dim3(512), dim3(512), 0, stream>>>(p0, p1, xxn, bufg, idx);
    k_qg   <<<dim3(512), dim3(256), 0, stream>>>(x, W, qg);
    k_out  <<<dim3(1024), dim3(256), 0, stream>>>(qg, idx, out);
}